// Round 10
// baseline (1083.683 us; speedup 1.0000x reference)
//
#include <hip/hip_runtime.h>

#define BATCH 4
#define SEQ   2048
#define EMBED 1024
#define HEADS 16
#define HDIM  64
#define NTOK  (BATCH*SEQ)

typedef __attribute__((ext_vector_type(8)))  short short8;   // 8 bf16 = MFMA A/B frag
typedef __attribute__((ext_vector_type(4)))  float f32x4;    // 16x16 C frag
typedef __attribute__((ext_vector_type(16))) float f32x16;   // 32x32 C frag

static __device__ __forceinline__ unsigned short f2bf(float f) {
    union { float f; unsigned u; } v; v.f = f;
    return (unsigned short)((v.u + 0x7FFFu + ((v.u >> 16) & 1u)) >> 16);  // RNE
}
// pack two floats -> bf16x2: single-instr HW convert (RNE), lo -> low 16
static __device__ __forceinline__ unsigned cvtpk(float lo, float hi) {
    unsigned r;
    asm("v_cvt_pk_bf16_f32 %0, %1, %2" : "=v"(r) : "v"(lo), "v"(hi));
    return r;
}
static __device__ __forceinline__ void gload_lds16(const unsigned short* g, unsigned short* l) {
    __builtin_amdgcn_global_load_lds(
        (__attribute__((address_space(1))) void*)g,
        (__attribute__((address_space(3))) void*)l, 16, 0, 0);
}

#define SCQ 0.180336880f   // log2(e)/8, folded into Q projection

// ---------------------------------------------------------------------------
// All fp32->bf16 casts in one launch: blocks [0,4096) = x, then 4x512 = weights
// ---------------------------------------------------------------------------
__global__ void cast_all(const float* __restrict__ x,
                         const float* __restrict__ w0, const float* __restrict__ w1,
                         const float* __restrict__ w2, const float* __restrict__ w3,
                         unsigned short* __restrict__ xb,
                         unsigned short* __restrict__ wb)
{
    const int bid = blockIdx.x;
    const float* src;
    unsigned short* dst;
    int i;
    if (bid < 4096) {
        src = x; dst = xb; i = (bid * 256 + threadIdx.x) * 8;
    } else {
        const int wz = (bid - 4096) >> 9;
        const float* ws[4] = {w0, w1, w2, w3};
        src = ws[wz];
        dst = wb + (size_t)wz * (EMBED * EMBED);
        i = (((bid - 4096) & 511) * 256 + threadIdx.x) * 8;
    }
    float4 a = *(const float4*)(src + i);
    float4 b = *(const float4*)(src + i + 4);
    union { int4 v; unsigned short u[8]; } pk;
    pk.u[0] = f2bf(a.x); pk.u[1] = f2bf(a.y); pk.u[2] = f2bf(a.z); pk.u[3] = f2bf(a.w);
    pk.u[4] = f2bf(b.x); pk.u[5] = f2bf(b.y); pk.u[6] = f2bf(b.z); pk.u[7] = f2bf(b.w);
    *(int4*)(dst + i) = pk.v;
}

// ---------------------------------------------------------------------------
// Fused QKV GEMM (R8 structure EXACTLY -- best total 266.4us; R9's 2-phase
// regressed). Two BK=32 buffers per barrier pair. Outputs: Q (pre-scaled),
// K row-major; V transposed, sigma-permuted cols (bits 2<->3 of s&15) so
// attn's PV B-frag equals raw cvtpk output. XCD-local token swizzle.
// ---------------------------------------------------------------------------
__global__ __launch_bounds__(256, 2)
void gemm_qkv(const unsigned short* __restrict__ Xb,
              const unsigned short* __restrict__ Wall,
              const float* __restrict__ bq, const float* __restrict__ bk,
              const float* __restrict__ bv,
              unsigned short* __restrict__ Qw, unsigned short* __restrict__ Kw,
              unsigned short* __restrict__ VtG)
{
    __shared__ unsigned short Ws[2][3][128][32];
    __shared__ unsigned short Xs[2][128][32];

    const int tid  = threadIdx.x;
    const int bx   = blockIdx.x, by = blockIdx.y;
    const int f0   = (by >> 3) * 128;                  // feature block 0..7
    const int t0   = ((bx << 3) | (by & 7)) * 128;     // token block: XCD-local
    const int lane = tid & 63, m = lane & 15, quad = lane >> 4;
    const int wid  = tid >> 6;
    const int wf   = (wid & 1) * 64;
    const int wt   = (wid >> 1) * 64;

    const int r    = tid >> 2, cc = tid & 3, sw = (tid >> 4) & 3;
    const int gcol = (cc ^ sw) << 3;
    const unsigned short* Xp = Xb + (size_t)(t0 + r) * EMBED + gcol;
    const unsigned short* Wp = Wall + (size_t)(f0 + r) * EMBED + gcol;
    unsigned short* XsL[2] = { &Xs[0][0][0] + tid * 8, &Xs[1][0][0] + tid * 8 };
    unsigned short* WsL[2] = { &Ws[0][0][0][0] + tid * 8, &Ws[1][0][0][0] + tid * 8 };

    const int qs = (quad ^ ((m >> 2) & 3)) << 3;

    f32x4 aq[4][4] = {}, ak[4][4] = {}, av[4][4] = {};

    for (int k0 = 0; k0 < EMBED; k0 += 64) {
        __syncthreads();
#pragma unroll
        for (int hf = 0; hf < 2; ++hf) {
            const int kk = k0 + hf * 32;
            gload_lds16(Xp + kk,              XsL[hf]);
            gload_lds16(Xp + kk + 64 * EMBED, XsL[hf] + 2048);
#pragma unroll
            for (int z = 0; z < 3; ++z) {
                const unsigned short* wz = Wp + (size_t)z * EMBED * EMBED + kk;
                gload_lds16(wz,              WsL[hf] + z * 4096);
                gload_lds16(wz + 64 * EMBED, WsL[hf] + z * 4096 + 2048);
            }
        }
        __syncthreads();

#pragma unroll
        for (int hf = 0; hf < 2; ++hf) {
            short8 bf4[4];
#pragma unroll
            for (int nb = 0; nb < 4; ++nb)
                bf4[nb] = *(const short8*)&Xs[hf][wt + nb * 16 + m][qs];

#pragma unroll
            for (int z = 0; z < 3; ++z) {
                short8 af[4];
#pragma unroll
                for (int mb = 0; mb < 4; ++mb)
                    af[mb] = *(const short8*)&Ws[hf][z][wf + mb * 16 + m][qs];
                f32x4 (&acc)[4][4] = (z == 0) ? aq : (z == 1) ? ak : av;
#pragma unroll
                for (int mb = 0; mb < 4; ++mb)
#pragma unroll
                    for (int nb = 0; nb < 4; ++nb)
                        acc[mb][nb] = __builtin_amdgcn_mfma_f32_16x16x32_bf16(
                            af[mb], bf4[nb], acc[mb][nb], 0, 0, 0);
            }
        }
    }

    // ---- Q epilogue (scaled by SCQ) ----
#pragma unroll
    for (int mb = 0; mb < 4; ++mb) {
        const int feat = f0 + wf + mb * 16 + quad * 4;
        float4 bv4 = *(const float4*)&bq[feat];
#pragma unroll
        for (int nb = 0; nb < 4; ++nb) {
            const int tok = t0 + wt + nb * 16 + m;
            ushort4 pk;
            pk.x = f2bf((aq[mb][nb][0] + bv4.x) * SCQ);
            pk.y = f2bf((aq[mb][nb][1] + bv4.y) * SCQ);
            pk.z = f2bf((aq[mb][nb][2] + bv4.z) * SCQ);
            pk.w = f2bf((aq[mb][nb][3] + bv4.w) * SCQ);
            *(ushort4*)(Qw + (size_t)tok * EMBED + feat) = pk;
        }
    }
    // ---- K epilogue ----
#pragma unroll
    for (int mb = 0; mb < 4; ++mb) {
        const int feat = f0 + wf + mb * 16 + quad * 4;
        float4 bv4 = *(const float4*)&bk[feat];
#pragma unroll
        for (int nb = 0; nb < 4; ++nb) {
            const int tok = t0 + wt + nb * 16 + m;
            ushort4 pk;
            pk.x = f2bf(ak[mb][nb][0] + bv4.x);
            pk.y = f2bf(ak[mb][nb][1] + bv4.y);
            pk.z = f2bf(ak[mb][nb][2] + bv4.z);
            pk.w = f2bf(ak[mb][nb][3] + bv4.w);
            *(ushort4*)(Kw + (size_t)tok * EMBED + feat) = pk;
        }
    }
    // ---- V epilogue: transposed, sigma-permuted column (bits 2<->3 of s&15) ----
    {
        const int h = (f0 + wf) >> 6;              // feat block is h-aligned (64)
#pragma unroll
        for (int nb = 0; nb < 4; ++nb) {
            const int tok = t0 + wt + nb * 16 + m;
            const int b   = tok >> 11;
            const int s   = tok & (SEQ - 1);
            const int sp  = (s & ~12) | ((s & 4) << 1) | ((s & 8) >> 1);
            const size_t base = ((size_t)(b * HEADS + h) * HDIM) * SEQ + sp;
#pragma unroll
            for (int mb = 0; mb < 4; ++mb) {
                const int feat  = f0 + wf + mb * 16 + quad * 4;
                const int dbase = mb * 16 + quad * 4;
                float4 bv4 = *(const float4*)&bv[feat];
                VtG[base + (size_t)(dbase + 0) * SEQ] = f2bf(av[mb][nb][0] + bv4.x);
                VtG[base + (size_t)(dbase + 1) * SEQ] = f2bf(av[mb][nb][1] + bv4.y);
                VtG[base + (size_t)(dbase + 2) * SEQ] = f2bf(av[mb][nb][2] + bv4.z);
                VtG[base + (size_t)(dbase + 3) * SEQ] = f2bf(av[mb][nb][3] + bv4.w);
            }
        }
    }
}

// ---------------------------------------------------------------------------
// MFMA flash attention, 32x32x16 -- R10 KEY-SPLIT x2.
// R2..R9 analysis: total waves at 32q/wave = 4096 = 16/CU -- the GRID capped
// occupancy at 50%; every within-wave latency trick failed because no spare
// waves existed to fill the QK->exp2->cvtpk->PV dependency chain. Splitting
// the key loop in half doubles blocks to 2048 = 8/CU; single-buffer LDS
// (18.4KB x 8 = 147KB) + VGPR<=64 -> 32 waves/CU (100%). No max-tracking is
// needed (p=exp2(s), masked p==0 exactly), so splits combine exactly:
// unnormalized O-partials (f32) + row-sums lr; attn_combine divides.
// Compute body = R7 verbatim (sigma-V direct B-frag, hoisted QK chains,
// mask bitmask, seed-MFMA mask fold, f32 tree lr, setprio). Loop = R2-proven
// single-buffer two-barrier (loads at top; cross-block TLP covers latency --
// now with 2x the blocks).
// ---------------------------------------------------------------------------
__global__ __launch_bounds__(256, 8)
void attn_mfma(const unsigned short* __restrict__ Qb,
               const unsigned short* __restrict__ Kb,
               const unsigned short* __restrict__ VtG,
               const int* __restrict__ mask,
               float* __restrict__ OpA, float* __restrict__ OpB,
               float* __restrict__ lrp)
{
    __shared__ unsigned short Ks[64][72];     // [key][d]
    __shared__ unsigned short Vs[64][72];     // [d][key-sigma]

    const int tid  = threadIdx.x;
    // XCD-local remap over 2048 blocks: XCD = bid % 8 gets 256 contiguous lin
    const int lin  = (blockIdx.x & 7) * 256 + (blockIdx.x >> 3);
    const int sp   = lin & 1;                 // key-split half
    const int qb   = (lin >> 1) & 15;
    const int h    = (lin >> 5) & 15;
    const int b    = lin >> 9;
    const int wid  = tid >> 6, lane = tid & 63;
    const int q32  = lane & 31, hi = lane >> 5;
    const int tb   = b * SEQ;
    const int q    = qb * 128 + wid * 32 + q32;
    const int kt0  = sp * 1024;

    // Q B-frags (pre-scaled): k = st*16 + hi*8 + j
    const unsigned short* qrow = Qb + (size_t)(tb + q) * EMBED + h * HDIM;
    short8 qf[4];
#pragma unroll
    for (int st = 0; st < 4; ++st)
        qf[st] = *(const short8*)(qrow + st * 16 + hi * 8);

    // mask bitmask: bit j = mask[j*32 + q32] (lane tests only keys == q32 mod 32)
    const int* mrow = mask + b * SEQ;
    unsigned long long mbits = 0;
#pragma unroll 8
    for (int j = 0; j < 64; ++j)
        mbits |= (unsigned long long)(mrow[j * 32 + q32] != 0 ? 1 : 0) << j;

    // mask B-frag: B[q][k]: nonzero only at k==0 (lanes hi==0, j==0)
    short8 mqf = {0, 0, 0, 0, 0, 0, 0, 0};
    mqf[0] = hi ? (short)0 : (short)0xC480;   // bf16(-1024), exact

    f32x16 o0, o1, z16;
#pragma unroll
    for (int i = 0; i < 16; ++i) { z16[i] = 0.f; }
    o0 = z16; o1 = z16;
    float lr = 0.f;

    // staging: thread -> (row = tid>>2, 16-elem col group = (tid&3)*16)
    const int sr = tid >> 2, sc = (tid & 3) * 16;
    const unsigned short* kSrc = Kb + (size_t)(tb + sr) * EMBED + h * HDIM + sc;
    const unsigned short* vSrc = VtG + ((size_t)(b * HEADS + h) * HDIM + sr) * SEQ + sc;

    for (int kt = kt0; kt < kt0 + 1024; kt += 64) {
        // loads for THIS tile at loop top; 8-blocks/CU TLP hides the latency
        int4 kv0 = *(const int4*)(kSrc + (size_t)kt * EMBED);
        int4 kv1 = *(const int4*)(kSrc + (size_t)kt * EMBED + 8);
        int4 vv0 = *(const int4*)(vSrc + kt);
        int4 vv1 = *(const int4*)(vSrc + kt + 8);
        __syncthreads();
        *(int4*)&Ks[sr][sc]     = kv0;
        *(int4*)&Ks[sr][sc + 8] = kv1;
        *(int4*)&Vs[sr][sc]     = vv0;
        *(int4*)&Vs[sr][sc + 8] = vv1;
        __syncthreads();

        const int jb = kt >> 5;
        __builtin_amdgcn_s_setprio(1);
        short8 mkfa = {0, 0, 0, 0, 0, 0, 0, 0};
        short8 mkfb = {0, 0, 0, 0, 0, 0, 0, 0};
        mkfa[0] = (hi == 0 && !((mbits >> jb) & 1))       ? (short)0x3F80 : (short)0;
        mkfb[0] = (hi == 0 && !((mbits >> (jb + 1)) & 1)) ? (short)0x3F80 : (short)0;

        // --- both QK^T chains first: matrix pipe fed during softmax below ---
        f32x16 s[2];
        s[0] = __builtin_amdgcn_mfma_f32_32x32x16_bf16(mkfa, mqf, z16, 0, 0, 0);
        s[1] = __builtin_amdgcn_mfma_f32_32x32x16_bf16(mkfb, mqf, z16, 0, 0, 0);
#pragma unroll
        for (int kb = 0; kb < 2; ++kb)
#pragma unroll
            for (int st = 0; st < 4; ++st) {
                short8 kf = *(const short8*)&Ks[kb * 32 + q32][st * 16 + hi * 8];
                s[kb] = __builtin_amdgcn_mfma_f32_32x32x16_bf16(kf, qf[st], s[kb], 0, 0, 0);
            }

#pragma unroll
        for (int kb = 0; kb < 2; ++kb) {
            // p = exp2(s); masked keys give exactly 0
            float p[16];
#pragma unroll
            for (int i = 0; i < 16; ++i) p[i] = __builtin_amdgcn_exp2f(s[kb][i]);

            // denominator: f32 tree-sum (masked p are exactly 0)
            lr += (((p[0] + p[1]) + (p[2] + p[3])) + ((p[4] + p[5]) + (p[6] + p[7])))
                + (((p[8] + p[9]) + (p[10] + p[11])) + ((p[12] + p[13]) + (p[14] + p[15])));

            unsigned D[8];
#pragma unroll
            for (int j = 0; j < 8; ++j) D[j] = cvtpk(p[2 * j], p[2 * j + 1]);

            // PV: B-frag = D directly (V is sigma-permuted); no permlane
#pragma unroll
            for (int cl = 0; cl < 2; ++cl) {
                union { uint4 u; short8 s8; } fr;
                fr.u.x = D[4 * cl + 0]; fr.u.y = D[4 * cl + 1];
                fr.u.z = D[4 * cl + 2]; fr.u.w = D[4 * cl + 3];

                const int kcol = kb * 32 + cl * 16 + hi * 8;
                short8 vf0 = *(const short8*)&Vs[q32][kcol];
                short8 vf1 = *(const short8*)&Vs[32 + q32][kcol];
                o0 = __builtin_amdgcn_mfma_f32_32x32x16_bf16(vf0, fr.s8, o0, 0, 0, 0);
                o1 = __builtin_amdgcn_mfma_f32_32x32x16_bf16(vf1, fr.s8, o1, 0, 0, 0);
            }
        }
        __builtin_amdgcn_s_setprio(0);
    }

    // per-split row-sum: combine hi halves, store once per q-row
    const float lrt = lr + __shfl_xor(lr, 32);
    const int li = ((b * HEADS + h) << 11) + q;
    if (hi == 0) lrp[sp * (BATCH * HEADS * SEQ) + li] = lrt;

    // unnormalized O partial, f32 (exactly the per-split accumulator)
    float* op = (sp ? OpB : OpA) + (size_t)(tb + q) * EMBED + h * HDIM;
#pragma unroll
    for (int db = 0; db < 2; ++db) {
        const f32x16& oo = db ? o1 : o0;
#pragma unroll
        for (int qg = 0; qg < 4; ++qg) {
            float4 st;
            st.x = oo[qg * 4 + 0]; st.y = oo[qg * 4 + 1];
            st.z = oo[qg * 4 + 2]; st.w = oo[qg * 4 + 3];
            *(float4*)(op + db * 32 + qg * 8 + hi * 4) = st;
        }
    }
}

// ---------------------------------------------------------------------------
// Combine the two key-split partials: Ow = (OpA + OpB) / (lrA + lrB), bf16.
// ---------------------------------------------------------------------------
__global__ void attn_combine(const float* __restrict__ OpA,
                             const float* __restrict__ OpB,
                             const float* __restrict__ lrp,
                             unsigned short* __restrict__ Ow)
{
    const int i0  = (blockIdx.x * 256 + threadIdx.x) * 8;
    const int tok = i0 >> 10;
    const int col = i0 & (EMBED - 1);
    const int h   = col >> 6;
    const int b   = tok >> 11;
    const int q   = tok & (SEQ - 1);
    const int li  = ((b * HEADS + h) << 11) + q;
    const float inv = 1.0f / (lrp[li] + lrp[BATCH * HEADS * SEQ + li]);

    float4 a0 = *(const float4*)(OpA + i0);
    float4 a1 = *(const float4*)(OpA + i0 + 4);
    float4 b0 = *(const float4*)(OpB + i0);
    float4 b1 = *(const float4*)(OpB + i0 + 4);
    union { int4 v; unsigned short u[8]; } pk;
    pk.u[0] = f2bf((a0.x + b0.x) * inv);
    pk.u[1] = f2bf((a0.y + b0.y) * inv);
    pk.u[2] = f2bf((a0.z + b0.z) * inv);
    pk.u[3] = f2bf((a0.w + b0.w) * inv);
    pk.u[4] = f2bf((a1.x + b1.x) * inv);
    pk.u[5] = f2bf((a1.y + b1.y) * inv);
    pk.u[6] = f2bf((a1.z + b1.z) * inv);
    pk.u[7] = f2bf((a1.w + b1.w) * inv);
    *(int4*)(Ow + i0) = pk.v;
}

// ---------------------------------------------------------------------------
// Output GEMM (R8 structure exactly). fp32 out. XCD-local token swizzle.
// ---------------------------------------------------------------------------
__global__ __launch_bounds__(256, 2)
void gemm_o(const unsigned short* __restrict__ W, const unsigned short* __restrict__ X,
            const float* __restrict__ bias, float* __restrict__ Cout)
{
    __shared__ unsigned short Ws[2][128][32];
    __shared__ unsigned short Xs[2][128][32];

    const int tid  = threadIdx.x;
    const int bx   = blockIdx.x, by = blockIdx.y;
    const int f0   = (by >> 3) * 128;
    const int t0   = ((bx << 3) | (by & 7)) * 128;
    const int lane = tid & 63, m = lane & 15, quad = lane >> 4;
    const int wid  = tid >> 6;
    const int wf   = (wid & 1) * 64;
    const int wt   = (wid >> 1) * 64;

    const int r    = tid >> 2, cc = tid & 3, sw = (tid >> 4) & 3;
    const int gcol = (cc ^ sw) << 3;
    const unsigned short* Wp = W + (size_t)(f0 + r) * EMBED + gcol;
    const unsigned short* Xp = X + (size_t)(t0 + r) * EMBED + gcol;
    unsigned short* WsL[2] = { &Ws[0][0][0] + tid * 8, &Ws[1][0][0] + tid * 8 };
    unsigned short* XsL[2] = { &Xs[0][0][0] + tid * 8, &Xs[1][0][0] + tid * 8 };

    const int qs = (quad ^ ((m >> 2) & 3)) << 3;

    f32x4 acc[4][4] = {};

    for (int k0 = 0; k0 < EMBED; k0 += 64) {
        __syncthreads();
#pragma unroll
        for (int hf = 0; hf < 2; ++hf) {
            const int kk = k0 + hf * 32;
            gload_lds16(Wp + kk,              WsL[hf]);
            gload_lds16(Wp + kk + 64 * EMBED, WsL[hf] + 2048);
            gload_lds16(Xp + kk,              XsL[hf]);
            gload_lds16(Xp + kk + 64 * EMBED, XsL[hf] + 2048);
        }
        __syncthreads();

#pragma unroll
        for (int hf = 0; hf < 2; ++hf) {
            short8 af[4], bf4[4];
#pragma unroll
            for (int mb = 0; mb < 4; ++mb)
                af[mb] = *(const short8*)&Ws[hf][wf + mb * 16 + m][qs];
#pragma unroll
            for (int nb = 0; nb < 4; ++nb)
                bf4[nb] = *(const short8*)&Xs[hf][wt + nb * 16 + m][qs];
#pragma unroll
            for (int mb = 0; mb < 4; ++mb)
#pragma unroll
                for (int nb = 0; nb < 4; ++nb)
                    acc[mb][nb] = __builtin_amdgcn_mfma_f32_16x16x32_bf16(
                        af[mb], bf4[nb], acc[mb][nb], 0, 0, 0);
        }
    }

#pragma unroll
    for (int mb = 0; mb < 4; ++mb) {
        const int feat = f0 + wf + mb * 16 + quad * 4;
        float4 bv4 = *(const float4*)&bias[feat];
#pragma unroll
        for (int nb = 0; nb < 4; ++nb) {
            const int tok = t0 + wt + nb * 16 + m;
            float4 st;
            st.x = acc[mb][nb][0] + bv4.x;
            st.y = acc[mb][nb][1] + bv4.y;
            st.z = acc[mb][nb][2] + bv4.z;
            st.w = acc[mb][nb][3] + bv4.w;
            *(float4*)(Cout + (size_t)tok * EMBED + feat) = st;
        }
    }
}

// ---------------------------------------------------------------------------
extern "C" void kernel_launch(void* const* d_in, const int* in_sizes, int n_in,
                              void* d_out, int out_size, void* d_ws, size_t ws_size,
                              hipStream_t stream)
{
    const float* x    = (const float*)d_in[0];
    const int*   mask = (const int*)  d_in[1];
    const float* Wq   = (const float*)d_in[2];
    const float* bq   = (const float*)d_in[3];
    const float* Wk   = (const float*)d_in[4];
    const float* bk   = (const float*)d_in[5];
    const float* Wv   = (const float*)d_in[6];
    const float* bv   = (const float*)d_in[7];
    const float* Wo   = (const float*)d_in[8];
    const float* bo   = (const float*)d_in[9];
    float* out = (float*)d_out;

    const size_t NE = (size_t)NTOK * EMBED;
    const size_t WE = (size_t)EMBED * EMBED;
    unsigned short* Xb  = (unsigned short*)d_ws;
    unsigned short* Wqb = Xb + NE;            // Wq,Wk,Wv,Wo contiguous
    unsigned short* Wob = Wqb + 3 * WE;
    unsigned short* Qw  = Wob + WE;
    unsigned short* Kw  = Qw + NE;
    unsigned short* VtG = Kw + NE;            // [b*H+h][d][s-sigma], d = 0..63
    float* OpA = (float*)(VtG + NE);          // key-split partial O (f32)
    float* OpB = OpA + NE;
    float* lrp = OpB + NE;                    // [2][B*H*SEQ] row sums
    unsigned short* Ow  = Xb;                 // reuse: Xb dead after projections

    cast_all<<<4096 + 2048, 256, 0, stream>>>(x, Wq, Wk, Wv, Wo, Xb, Wqb);

    gemm_qkv<<<dim3(8, 64), 256, 0, stream>>>(Xb, Wqb, bq, bk, bv, Qw, Kw, VtG);

    attn_mfma<<<2 * BATCH * HEADS * (SEQ / 128), 256, 0, stream>>>(
        Qw, Kw, VtG, mask, OpA, OpB, lrp);

    attn_combine<<<NE / (256 * 8), 256, 0, stream>>>(OpA, OpB, lrp, Ow);

    gemm_o<<<dim3(8, 64), 256, 0, stream>>>(Wob, Ow, bo, out);
}

// Round 11
// 284.856 us; speedup vs baseline: 3.8043x; 3.8043x over previous
//
#include <hip/hip_runtime.h>

#define BATCH 4
#define SEQ   2048
#define EMBED 1024
#define HEADS 16
#define HDIM  64
#define NTOK  (BATCH*SEQ)

typedef __attribute__((ext_vector_type(8)))  short short8;   // 8 bf16 = MFMA A/B frag
typedef __attribute__((ext_vector_type(4)))  float f32x4;    // 16x16 C frag
typedef __attribute__((ext_vector_type(16))) float f32x16;   // 32x32 C frag

static __device__ __forceinline__ unsigned short f2bf(float f) {
    union { float f; unsigned u; } v; v.f = f;
    return (unsigned short)((v.u + 0x7FFFu + ((v.u >> 16) & 1u)) >> 16);  // RNE
}
// pack two floats -> bf16x2: single-instr HW convert (RNE), lo -> low 16
static __device__ __forceinline__ unsigned cvtpk(float lo, float hi) {
    unsigned r;
    asm("v_cvt_pk_bf16_f32 %0, %1, %2" : "=v"(r) : "v"(lo), "v"(hi));
    return r;
}
static __device__ __forceinline__ void gload_lds16(const unsigned short* g, unsigned short* l) {
    __builtin_amdgcn_global_load_lds(
        (__attribute__((address_space(1))) void*)g,
        (__attribute__((address_space(3))) void*)l, 16, 0, 0);
}

#define SCQ 0.180336880f   // log2(e)/8, folded into Q projection

// ---------------------------------------------------------------------------
// All fp32->bf16 casts in one launch: blocks [0,4096) = x, then 4x512 = weights
// ---------------------------------------------------------------------------
__global__ void cast_all(const float* __restrict__ x,
                         const float* __restrict__ w0, const float* __restrict__ w1,
                         const float* __restrict__ w2, const float* __restrict__ w3,
                         unsigned short* __restrict__ xb,
                         unsigned short* __restrict__ wb)
{
    const int bid = blockIdx.x;
    const float* src;
    unsigned short* dst;
    int i;
    if (bid < 4096) {
        src = x; dst = xb; i = (bid * 256 + threadIdx.x) * 8;
    } else {
        const int wz = (bid - 4096) >> 9;
        const float* ws[4] = {w0, w1, w2, w3};
        src = ws[wz];
        dst = wb + (size_t)wz * (EMBED * EMBED);
        i = (((bid - 4096) & 511) * 256 + threadIdx.x) * 8;
    }
    float4 a = *(const float4*)(src + i);
    float4 b = *(const float4*)(src + i + 4);
    union { int4 v; unsigned short u[8]; } pk;
    pk.u[0] = f2bf(a.x); pk.u[1] = f2bf(a.y); pk.u[2] = f2bf(a.z); pk.u[3] = f2bf(a.w);
    pk.u[4] = f2bf(b.x); pk.u[5] = f2bf(b.y); pk.u[6] = f2bf(b.z); pk.u[7] = f2bf(b.w);
    *(int4*)(dst + i) = pk.v;
}

// ---------------------------------------------------------------------------
// Fused QKV GEMM (R8 structure EXACTLY -- best total 266.4us). Two BK=32
// buffers per barrier pair. Outputs: Q (pre-scaled), K row-major; V
// transposed, sigma-permuted cols (bits 2<->3 of s&15) so attn's PV B-frag
// equals raw cvtpk output. XCD-local token swizzle.
// ---------------------------------------------------------------------------
__global__ __launch_bounds__(256, 2)
void gemm_qkv(const unsigned short* __restrict__ Xb,
              const unsigned short* __restrict__ Wall,
              const float* __restrict__ bq, const float* __restrict__ bk,
              const float* __restrict__ bv,
              unsigned short* __restrict__ Qw, unsigned short* __restrict__ Kw,
              unsigned short* __restrict__ VtG)
{
    __shared__ unsigned short Ws[2][3][128][32];
    __shared__ unsigned short Xs[2][128][32];

    const int tid  = threadIdx.x;
    const int bx   = blockIdx.x, by = blockIdx.y;
    const int f0   = (by >> 3) * 128;                  // feature block 0..7
    const int t0   = ((bx << 3) | (by & 7)) * 128;     // token block: XCD-local
    const int lane = tid & 63, m = lane & 15, quad = lane >> 4;
    const int wid  = tid >> 6;
    const int wf   = (wid & 1) * 64;
    const int wt   = (wid >> 1) * 64;

    const int r    = tid >> 2, cc = tid & 3, sw = (tid >> 4) & 3;
    const int gcol = (cc ^ sw) << 3;
    const unsigned short* Xp = Xb + (size_t)(t0 + r) * EMBED + gcol;
    const unsigned short* Wp = Wall + (size_t)(f0 + r) * EMBED + gcol;
    unsigned short* XsL[2] = { &Xs[0][0][0] + tid * 8, &Xs[1][0][0] + tid * 8 };
    unsigned short* WsL[2] = { &Ws[0][0][0][0] + tid * 8, &Ws[1][0][0][0] + tid * 8 };

    const int qs = (quad ^ ((m >> 2) & 3)) << 3;

    f32x4 aq[4][4] = {}, ak[4][4] = {}, av[4][4] = {};

    for (int k0 = 0; k0 < EMBED; k0 += 64) {
        __syncthreads();
#pragma unroll
        for (int hf = 0; hf < 2; ++hf) {
            const int kk = k0 + hf * 32;
            gload_lds16(Xp + kk,              XsL[hf]);
            gload_lds16(Xp + kk + 64 * EMBED, XsL[hf] + 2048);
#pragma unroll
            for (int z = 0; z < 3; ++z) {
                const unsigned short* wz = Wp + (size_t)z * EMBED * EMBED + kk;
                gload_lds16(wz,              WsL[hf] + z * 4096);
                gload_lds16(wz + 64 * EMBED, WsL[hf] + z * 4096 + 2048);
            }
        }
        __syncthreads();

#pragma unroll
        for (int hf = 0; hf < 2; ++hf) {
            short8 bf4[4];
#pragma unroll
            for (int nb = 0; nb < 4; ++nb)
                bf4[nb] = *(const short8*)&Xs[hf][wt + nb * 16 + m][qs];

#pragma unroll
            for (int z = 0; z < 3; ++z) {
                short8 af[4];
#pragma unroll
                for (int mb = 0; mb < 4; ++mb)
                    af[mb] = *(const short8*)&Ws[hf][z][wf + mb * 16 + m][qs];
                f32x4 (&acc)[4][4] = (z == 0) ? aq : (z == 1) ? ak : av;
#pragma unroll
                for (int mb = 0; mb < 4; ++mb)
#pragma unroll
                    for (int nb = 0; nb < 4; ++nb)
                        acc[mb][nb] = __builtin_amdgcn_mfma_f32_16x16x32_bf16(
                            af[mb], bf4[nb], acc[mb][nb], 0, 0, 0);
            }
        }
    }

    // ---- Q epilogue (scaled by SCQ) ----
#pragma unroll
    for (int mb = 0; mb < 4; ++mb) {
        const int feat = f0 + wf + mb * 16 + quad * 4;
        float4 bv4 = *(const float4*)&bq[feat];
#pragma unroll
        for (int nb = 0; nb < 4; ++nb) {
            const int tok = t0 + wt + nb * 16 + m;
            ushort4 pk;
            pk.x = f2bf((aq[mb][nb][0] + bv4.x) * SCQ);
            pk.y = f2bf((aq[mb][nb][1] + bv4.y) * SCQ);
            pk.z = f2bf((aq[mb][nb][2] + bv4.z) * SCQ);
            pk.w = f2bf((aq[mb][nb][3] + bv4.w) * SCQ);
            *(ushort4*)(Qw + (size_t)tok * EMBED + feat) = pk;
        }
    }
    // ---- K epilogue ----
#pragma unroll
    for (int mb = 0; mb < 4; ++mb) {
        const int feat = f0 + wf + mb * 16 + quad * 4;
        float4 bv4 = *(const float4*)&bk[feat];
#pragma unroll
        for (int nb = 0; nb < 4; ++nb) {
            const int tok = t0 + wt + nb * 16 + m;
            ushort4 pk;
            pk.x = f2bf(ak[mb][nb][0] + bv4.x);
            pk.y = f2bf(ak[mb][nb][1] + bv4.y);
            pk.z = f2bf(ak[mb][nb][2] + bv4.z);
            pk.w = f2bf(ak[mb][nb][3] + bv4.w);
            *(ushort4*)(Kw + (size_t)tok * EMBED + feat) = pk;
        }
    }
    // ---- V epilogue: transposed, sigma-permuted column (bits 2<->3 of s&15) ----
    {
        const int h = (f0 + wf) >> 6;              // feat block is h-aligned (64)
#pragma unroll
        for (int nb = 0; nb < 4; ++nb) {
            const int tok = t0 + wt + nb * 16 + m;
            const int b   = tok >> 11;
            const int s   = tok & (SEQ - 1);
            const int sp  = (s & ~12) | ((s & 4) << 1) | ((s & 8) >> 1);
            const size_t base = ((size_t)(b * HEADS + h) * HDIM) * SEQ + sp;
#pragma unroll
            for (int mb = 0; mb < 4; ++mb) {
                const int feat  = f0 + wf + mb * 16 + quad * 4;
                const int dbase = mb * 16 + quad * 4;
                float4 bv4 = *(const float4*)&bv[feat];
                VtG[base + (size_t)(dbase + 0) * SEQ] = f2bf(av[mb][nb][0] + bv4.x);
                VtG[base + (size_t)(dbase + 1) * SEQ] = f2bf(av[mb][nb][1] + bv4.y);
                VtG[base + (size_t)(dbase + 2) * SEQ] = f2bf(av[mb][nb][2] + bv4.z);
                VtG[base + (size_t)(dbase + 3) * SEQ] = f2bf(av[mb][nb][3] + bv4.w);
            }
        }
    }
}

// ---------------------------------------------------------------------------
// MFMA flash attention, 32x32x16 -- KEY-SPLIT x2, take two.
// R10 confirmed the occupancy mechanism (69.7%!) but __launch_bounds__(256,8)
// forced the allocator to 32 VGPR -> accumulator spills -> 4GB scratch traffic
// (907us). Fix: R7-proven (256,4) bound -- R7's near-identical body compiled
// to exactly 64 VGPR, and 64 VGPR + 18.4KB LDS admits 8 blocks/CU in HARDWARE
// (the bound is a floor request, not an occupancy cap).
// Key-split: blocks 2048, each does 16 key-tiles; no max-tracking needed
// (p=exp2(s), masked p==0 exactly) so splits combine exactly via f32
// partials + row-sums; attn_combine divides.
// ---------------------------------------------------------------------------
__global__ __launch_bounds__(256, 4)
void attn_mfma(const unsigned short* __restrict__ Qb,
               const unsigned short* __restrict__ Kb,
               const unsigned short* __restrict__ VtG,
               const int* __restrict__ mask,
               float* __restrict__ OpA, float* __restrict__ OpB,
               float* __restrict__ lrp)
{
    __shared__ unsigned short Ks[64][72];     // [key][d]
    __shared__ unsigned short Vs[64][72];     // [d][key-sigma]

    const int tid  = threadIdx.x;
    // XCD-local remap over 2048 blocks: XCD = bid % 8 gets 256 contiguous lin
    const int lin  = (blockIdx.x & 7) * 256 + (blockIdx.x >> 3);
    const int sp   = lin & 1;                 // key-split half
    const int qb   = (lin >> 1) & 15;
    const int h    = (lin >> 5) & 15;
    const int b    = lin >> 9;
    const int wid  = tid >> 6, lane = tid & 63;
    const int q32  = lane & 31, hi = lane >> 5;
    const int tb   = b * SEQ;
    const int q    = qb * 128 + wid * 32 + q32;
    const int kt0  = sp * 1024;

    // Q B-frags (pre-scaled): k = st*16 + hi*8 + j
    const unsigned short* qrow = Qb + (size_t)(tb + q) * EMBED + h * HDIM;
    short8 qf[4];
#pragma unroll
    for (int st = 0; st < 4; ++st)
        qf[st] = *(const short8*)(qrow + st * 16 + hi * 8);

    // mask bitmask for THIS half: bit j = mask[kt0 + j*32 + q32] (32 bits used)
    const int* mrow = mask + b * SEQ + kt0;
    unsigned mbits = 0;
#pragma unroll 8
    for (int j = 0; j < 32; ++j)
        mbits |= (unsigned)(mrow[j * 32 + q32] != 0 ? 1 : 0) << j;

    // mask B-frag: B[q][k]: nonzero only at k==0 (lanes hi==0, j==0)
    short8 mqf = {0, 0, 0, 0, 0, 0, 0, 0};
    mqf[0] = hi ? (short)0 : (short)0xC480;   // bf16(-1024), exact

    f32x16 o0, o1, z16;
#pragma unroll
    for (int i = 0; i < 16; ++i) { z16[i] = 0.f; }
    o0 = z16; o1 = z16;
    float lr = 0.f;

    // staging: thread -> (row = tid>>2, 16-elem col group = (tid&3)*16)
    const int sr = tid >> 2, sc = (tid & 3) * 16;
    const unsigned short* kSrc = Kb + (size_t)(tb + kt0 + sr) * EMBED + h * HDIM + sc;
    const unsigned short* vSrc = VtG + ((size_t)(b * HEADS + h) * HDIM + sr) * SEQ + kt0 + sc;

    for (int kt = 0; kt < 1024; kt += 64) {
        // loads for THIS tile at loop top; 8-blocks/CU TLP hides the latency
        int4 kv0 = *(const int4*)(kSrc + (size_t)kt * EMBED);
        int4 kv1 = *(const int4*)(kSrc + (size_t)kt * EMBED + 8);
        int4 vv0 = *(const int4*)(vSrc + kt);
        int4 vv1 = *(const int4*)(vSrc + kt + 8);
        __syncthreads();
        *(int4*)&Ks[sr][sc]     = kv0;
        *(int4*)&Ks[sr][sc + 8] = kv1;
        *(int4*)&Vs[sr][sc]     = vv0;
        *(int4*)&Vs[sr][sc + 8] = vv1;
        __syncthreads();

        const int jb = kt >> 5;
        __builtin_amdgcn_s_setprio(1);
        short8 mkfa = {0, 0, 0, 0, 0, 0, 0, 0};
        short8 mkfb = {0, 0, 0, 0, 0, 0, 0, 0};
        mkfa[0] = (hi == 0 && !((mbits >> jb) & 1))       ? (short)0x3F80 : (short)0;
        mkfb[0] = (hi == 0 && !((mbits >> (jb + 1)) & 1)) ? (short)0x3F80 : (short)0;

        // --- both QK^T chains first: matrix pipe fed during softmax below ---
        f32x16 s[2];
        s[0] = __builtin_amdgcn_mfma_f32_32x32x16_bf16(mkfa, mqf, z16, 0, 0, 0);
        s[1] = __builtin_amdgcn_mfma_f32_32x32x16_bf16(mkfb, mqf, z16, 0, 0, 0);
#pragma unroll
        for (int kb = 0; kb < 2; ++kb)
#pragma unroll
            for (int st = 0; st < 4; ++st) {
                short8 kf = *(const short8*)&Ks[kb * 32 + q32][st * 16 + hi * 8];
                s[kb] = __builtin_amdgcn_mfma_f32_32x32x16_bf16(kf, qf[st], s[kb], 0, 0, 0);
            }

#pragma unroll
        for (int kb = 0; kb < 2; ++kb) {
            // p = exp2(s); masked keys give exactly 0
            float p[16];
#pragma unroll
            for (int i = 0; i < 16; ++i) p[i] = __builtin_amdgcn_exp2f(s[kb][i]);

            // denominator: f32 tree-sum (masked p are exactly 0)
            lr += (((p[0] + p[1]) + (p[2] + p[3])) + ((p[4] + p[5]) + (p[6] + p[7])))
                + (((p[8] + p[9]) + (p[10] + p[11])) + ((p[12] + p[13]) + (p[14] + p[15])));

            unsigned D[8];
#pragma unroll
            for (int j = 0; j < 8; ++j) D[j] = cvtpk(p[2 * j], p[2 * j + 1]);

            // PV: B-frag = D directly (V is sigma-permuted); no permlane
#pragma unroll
            for (int cl = 0; cl < 2; ++cl) {
                union { uint4 u; short8 s8; } fr;
                fr.u.x = D[4 * cl + 0]; fr.u.y = D[4 * cl + 1];
                fr.u.z = D[4 * cl + 2]; fr.u.w = D[4 * cl + 3];

                const int kcol = kb * 32 + cl * 16 + hi * 8;
                short8 vf0 = *(const short8*)&Vs[q32][kcol];
                short8 vf1 = *(const short8*)&Vs[32 + q32][kcol];
                o0 = __builtin_amdgcn_mfma_f32_32x32x16_bf16(vf0, fr.s8, o0, 0, 0, 0);
                o1 = __builtin_amdgcn_mfma_f32_32x32x16_bf16(vf1, fr.s8, o1, 0, 0, 0);
            }
        }
        __builtin_amdgcn_s_setprio(0);
    }

    // per-split row-sum: combine hi halves, store once per q-row
    const float lrt = lr + __shfl_xor(lr, 32);
    const int li = ((b * HEADS + h) << 11) + q;
    if (hi == 0) lrp[sp * (BATCH * HEADS * SEQ) + li] = lrt;

    // unnormalized O partial, f32 (exactly the per-split accumulator)
    float* op = (sp ? OpB : OpA) + (size_t)(tb + q) * EMBED + h * HDIM;
#pragma unroll
    for (int db = 0; db < 2; ++db) {
        const f32x16& oo = db ? o1 : o0;
#pragma unroll
        for (int qg = 0; qg < 4; ++qg) {
            float4 st;
            st.x = oo[qg * 4 + 0]; st.y = oo[qg * 4 + 1];
            st.z = oo[qg * 4 + 2]; st.w = oo[qg * 4 + 3];
            *(float4*)(op + db * 32 + qg * 8 + hi * 4) = st;
        }
    }
}

// ---------------------------------------------------------------------------
// Combine the two key-split partials: Ow = (OpA + OpB) / (lrA + lrB), bf16.
// ---------------------------------------------------------------------------
__global__ void attn_combine(const float* __restrict__ OpA,
                             const float* __restrict__ OpB,
                             const float* __restrict__ lrp,
                             unsigned short* __restrict__ Ow)
{
    const int i0  = (blockIdx.x * 256 + threadIdx.x) * 8;
    const int tok = i0 >> 10;
    const int col = i0 & (EMBED - 1);
    const int h   = col >> 6;
    const int b   = tok >> 11;
    const int q   = tok & (SEQ - 1);
    const int li  = ((b * HEADS + h) << 11) + q;
    const float inv = 1.0f / (lrp[li] + lrp[BATCH * HEADS * SEQ + li]);

    float4 a0 = *(const float4*)(OpA + i0);
    float4 a1 = *(const float4*)(OpA + i0 + 4);
    float4 b0 = *(const float4*)(OpB + i0);
    float4 b1 = *(const float4*)(OpB + i0 + 4);
    union { int4 v; unsigned short u[8]; } pk;
    pk.u[0] = f2bf((a0.x + b0.x) * inv);
    pk.u[1] = f2bf((a0.y + b0.y) * inv);
    pk.u[2] = f2bf((a0.z + b0.z) * inv);
    pk.u[3] = f2bf((a0.w + b0.w) * inv);
    pk.u[4] = f2bf((a1.x + b1.x) * inv);
    pk.u[5] = f2bf((a1.y + b1.y) * inv);
    pk.u[6] = f2bf((a1.z + b1.z) * inv);
    pk.u[7] = f2bf((a1.w + b1.w) * inv);
    *(int4*)(Ow + i0) = pk.v;
}

// ---------------------------------------------------------------------------
// Output GEMM (R8 structure exactly). fp32 out. XCD-local token swizzle.
// ---------------------------------------------------------------------------
__global__ __launch_bounds__(256, 2)
void gemm_o(const unsigned short* __restrict__ W, const unsigned short* __restrict__ X,
            const float* __restrict__ bias, float* __restrict__ Cout)
{
    __shared__ unsigned short Ws[2][128][32];
    __shared__ unsigned short Xs[2][128][32];

    const int tid  = threadIdx.x;
    const int bx   = blockIdx.x, by = blockIdx.y;
    const int f0   = (by >> 3) * 128;
    const int t0   = ((bx << 3) | (by & 7)) * 128;
    const int lane = tid & 63, m = lane & 15, quad = lane >> 4;
    const int wid  = tid >> 6;
    const int wf   = (wid & 1) * 64;
    const int wt   = (wid >> 1) * 64;

    const int r    = tid >> 2, cc = tid & 3, sw = (tid >> 4) & 3;
    const int gcol = (cc ^ sw) << 3;
    const unsigned short* Wp = W + (size_t)(f0 + r) * EMBED + gcol;
    const unsigned short* Xp = X + (size_t)(t0 + r) * EMBED + gcol;
    unsigned short* WsL[2] = { &Ws[0][0][0] + tid * 8, &Ws[1][0][0] + tid * 8 };
    unsigned short* XsL[2] = { &Xs[0][0][0] + tid * 8, &Xs[1][0][0] + tid * 8 };

    const int qs = (quad ^ ((m >> 2) & 3)) << 3;

    f32x4 acc[4][4] = {};

    for (int k0 = 0; k0 < EMBED; k0 += 64) {
        __syncthreads();
#pragma unroll
        for (int hf = 0; hf < 2; ++hf) {
            const int kk = k0 + hf * 32;
            gload_lds16(Wp + kk,              WsL[hf]);
            gload_lds16(Wp + kk + 64 * EMBED, WsL[hf] + 2048);
            gload_lds16(Xp + kk,              XsL[hf]);
            gload_lds16(Xp + kk + 64 * EMBED, XsL[hf] + 2048);
        }
        __syncthreads();

#pragma unroll
        for (int hf = 0; hf < 2; ++hf) {
            short8 af[4], bf4[4];
#pragma unroll
            for (int mb = 0; mb < 4; ++mb)
                af[mb] = *(const short8*)&Ws[hf][wf + mb * 16 + m][qs];
#pragma unroll
            for (int nb = 0; nb < 4; ++nb)
                bf4[nb] = *(const short8*)&Xs[hf][wt + nb * 16 + m][qs];
#pragma unroll
            for (int mb = 0; mb < 4; ++mb)
#pragma unroll
                for (int nb = 0; nb < 4; ++nb)
                    acc[mb][nb] = __builtin_amdgcn_mfma_f32_16x16x32_bf16(
                        af[mb], bf4[nb], acc[mb][nb], 0, 0, 0);
        }
    }

#pragma unroll
    for (int mb = 0; mb < 4; ++mb) {
        const int feat = f0 + wf + mb * 16 + quad * 4;
        float4 bv4 = *(const float4*)&bias[feat];
#pragma unroll
        for (int nb = 0; nb < 4; ++nb) {
            const int tok = t0 + wt + nb * 16 + m;
            float4 st;
            st.x = acc[mb][nb][0] + bv4.x;
            st.y = acc[mb][nb][1] + bv4.y;
            st.z = acc[mb][nb][2] + bv4.z;
            st.w = acc[mb][nb][3] + bv4.w;
            *(float4*)(Cout + (size_t)tok * EMBED + feat) = st;
        }
    }
}

// ---------------------------------------------------------------------------
extern "C" void kernel_launch(void* const* d_in, const int* in_sizes, int n_in,
                              void* d_out, int out_size, void* d_ws, size_t ws_size,
                              hipStream_t stream)
{
    const float* x    = (const float*)d_in[0];
    const int*   mask = (const int*)  d_in[1];
    const float* Wq   = (const float*)d_in[2];
    const float* bq   = (const float*)d_in[3];
    const float* Wk   = (const float*)d_in[4];
    const float* bk   = (const float*)d_in[5];
    const float* Wv   = (const float*)d_in[6];
    const float* bv   = (const float*)d_in[7];
    const float* Wo   = (const float*)d_in[8];
    const float* bo   = (const float*)d_in[9];
    float* out = (float*)d_out;

    const size_t NE = (size_t)NTOK * EMBED;
    const size_t WE = (size_t)EMBED * EMBED;
    unsigned short* Xb  = (unsigned short*)d_ws;
    unsigned short* Wqb = Xb + NE;            // Wq,Wk,Wv,Wo contiguous
    unsigned short* Wob = Wqb + 3 * WE;
    unsigned short* Qw  = Wob + WE;
    unsigned short* Kw  = Qw + NE;
    unsigned short* VtG = Kw + NE;            // [b*H+h][d][s-sigma], d = 0..63
    float* OpA = (float*)(VtG + NE);          // key-split partial O (f32)
    float* OpB = OpA + NE;
    float* lrp = OpB + NE;                    // [2][B*H*SEQ] row sums
    unsigned short* Ow  = Xb;                 // reuse: Xb dead after projections

    cast_all<<<4096 + 2048, 256, 0, stream>>>(x, Wq, Wk, Wv, Wo, Xb, Wqb);

    gemm_qkv<<<dim3(8, 64), 256, 0, stream>>>(Xb, Wqb, bq, bk, bv, Qw, Kw, VtG);

    attn_mfma<<<2 * BATCH * HEADS * (SEQ / 128), 256, 0, stream>>>(
        Qw, Kw, VtG, mask, OpA, OpB, lrp);

    attn_combine<<<NE / (256 * 8), 256, 0, stream>>>(OpA, OpB, lrp, Ow);

    gemm_o<<<dim3(8, 64), 256, 0, stream>>>(Wob, Ow, bo, out);
}

// Round 13
// 263.417 us; speedup vs baseline: 4.1140x; 1.0814x over previous
//
#include <hip/hip_runtime.h>

#define BATCH 4
#define SEQ   2048
#define EMBED 1024
#define HEADS 16
#define HDIM  64
#define NTOK  (BATCH*SEQ)

typedef __attribute__((ext_vector_type(8)))  short short8;   // 8 bf16 = MFMA A/B frag
typedef __attribute__((ext_vector_type(4)))  float f32x4;    // 16x16 C frag
typedef __attribute__((ext_vector_type(16))) float f32x16;   // 32x32 C frag

static __device__ __forceinline__ unsigned short f2bf(float f) {
    union { float f; unsigned u; } v; v.f = f;
    return (unsigned short)((v.u + 0x7FFFu + ((v.u >> 16) & 1u)) >> 16);  // RNE
}
// pack two floats -> bf16x2: single-instr HW convert (RNE), lo -> low 16
static __device__ __forceinline__ unsigned cvtpk(float lo, float hi) {
    unsigned r;
    asm("v_cvt_pk_bf16_f32 %0, %1, %2" : "=v"(r) : "v"(lo), "v"(hi));
    return r;
}
static __device__ __forceinline__ void gload_lds16(const unsigned short* g, unsigned short* l) {
    __builtin_amdgcn_global_load_lds(
        (__attribute__((address_space(1))) void*)g,
        (__attribute__((address_space(3))) void*)l, 16, 0, 0);
}

#define SCQ 0.180336880f   // log2(e)/8, folded into Q projection

// ---------------------------------------------------------------------------
// All fp32->bf16 casts in one launch: blocks [0,4096) = x, then 4x512 = weights
// ---------------------------------------------------------------------------
__global__ void cast_all(const float* __restrict__ x,
                         const float* __restrict__ w0, const float* __restrict__ w1,
                         const float* __restrict__ w2, const float* __restrict__ w3,
                         unsigned short* __restrict__ xb,
                         unsigned short* __restrict__ wb)
{
    const int bid = blockIdx.x;
    const float* src;
    unsigned short* dst;
    int i;
    if (bid < 4096) {
        src = x; dst = xb; i = (bid * 256 + threadIdx.x) * 8;
    } else {
        const int wz = (bid - 4096) >> 9;
        const float* ws[4] = {w0, w1, w2, w3};
        src = ws[wz];
        dst = wb + (size_t)wz * (EMBED * EMBED);
        i = (((bid - 4096) & 511) * 256 + threadIdx.x) * 8;
    }
    float4 a = *(const float4*)(src + i);
    float4 b = *(const float4*)(src + i + 4);
    union { int4 v; unsigned short u[8]; } pk;
    pk.u[0] = f2bf(a.x); pk.u[1] = f2bf(a.y); pk.u[2] = f2bf(a.z); pk.u[3] = f2bf(a.w);
    pk.u[4] = f2bf(b.x); pk.u[5] = f2bf(b.y); pk.u[6] = f2bf(b.z); pk.u[7] = f2bf(b.w);
    *(int4*)(dst + i) = pk.v;
}

// ---------------------------------------------------------------------------
// Fused QKV GEMM (R8 structure -- best verified total 266.4us). Two BK=32
// buffers per barrier pair. Outputs: Q (pre-scaled SCQ), K row-major; V
// transposed, sigma-permuted cols (bits 2<->3 of s&15) so attn's PV B-frag
// equals raw cvtpk output. XCD-local token swizzle.
// ---------------------------------------------------------------------------
__global__ __launch_bounds__(256, 2)
void gemm_qkv(const unsigned short* __restrict__ Xb,
              const unsigned short* __restrict__ Wall,
              const float* __restrict__ bq, const float* __restrict__ bk,
              const float* __restrict__ bv,
              unsigned short* __restrict__ Qw, unsigned short* __restrict__ Kw,
              unsigned short* __restrict__ VtG)
{
    __shared__ unsigned short Ws[2][3][128][32];
    __shared__ unsigned short Xs[2][128][32];

    const int tid  = threadIdx.x;
    const int bx   = blockIdx.x, by = blockIdx.y;
    const int f0   = (by >> 3) * 128;                  // feature block 0..7
    const int t0   = ((bx << 3) | (by & 7)) * 128;     // token block: XCD-local
    const int lane = tid & 63, m = lane & 15, quad = lane >> 4;
    const int wid  = tid >> 6;
    const int wf   = (wid & 1) * 64;
    const int wt   = (wid >> 1) * 64;

    const int r    = tid >> 2, cc = tid & 3, sw = (tid >> 4) & 3;
    const int gcol = (cc ^ sw) << 3;
    const unsigned short* Xp = Xb + (size_t)(t0 + r) * EMBED + gcol;
    const unsigned short* Wp = Wall + (size_t)(f0 + r) * EMBED + gcol;
    unsigned short* XsL[2] = { &Xs[0][0][0] + tid * 8, &Xs[1][0][0] + tid * 8 };
    unsigned short* WsL[2] = { &Ws[0][0][0][0] + tid * 8, &Ws[1][0][0][0] + tid * 8 };

    const int qs = (quad ^ ((m >> 2) & 3)) << 3;

    f32x4 aq[4][4] = {}, ak[4][4] = {}, av[4][4] = {};

    for (int k0 = 0; k0 < EMBED; k0 += 64) {
        __syncthreads();
#pragma unroll
        for (int hf = 0; hf < 2; ++hf) {
            const int kk = k0 + hf * 32;
            gload_lds16(Xp + kk,              XsL[hf]);
            gload_lds16(Xp + kk + 64 * EMBED, XsL[hf] + 2048);
#pragma unroll
            for (int z = 0; z < 3; ++z) {
                const unsigned short* wz = Wp + (size_t)z * EMBED * EMBED + kk;
                gload_lds16(wz,              WsL[hf] + z * 4096);
                gload_lds16(wz + 64 * EMBED, WsL[hf] + z * 4096 + 2048);
            }
        }
        __syncthreads();

#pragma unroll
        for (int hf = 0; hf < 2; ++hf) {
            short8 bf4[4];
#pragma unroll
            for (int nb = 0; nb < 4; ++nb)
                bf4[nb] = *(const short8*)&Xs[hf][wt + nb * 16 + m][qs];

#pragma unroll
            for (int z = 0; z < 3; ++z) {
                short8 af[4];
#pragma unroll
                for (int mb = 0; mb < 4; ++mb)
                    af[mb] = *(const short8*)&Ws[hf][z][wf + mb * 16 + m][qs];
                f32x4 (&acc)[4][4] = (z == 0) ? aq : (z == 1) ? ak : av;
#pragma unroll
                for (int mb = 0; mb < 4; ++mb)
#pragma unroll
                    for (int nb = 0; nb < 4; ++nb)
                        acc[mb][nb] = __builtin_amdgcn_mfma_f32_16x16x32_bf16(
                            af[mb], bf4[nb], acc[mb][nb], 0, 0, 0);
            }
        }
    }

    // ---- Q epilogue (scaled by SCQ) ----
#pragma unroll
    for (int mb = 0; mb < 4; ++mb) {
        const int feat = f0 + wf + mb * 16 + quad * 4;
        float4 bv4 = *(const float4*)&bq[feat];
#pragma unroll
        for (int nb = 0; nb < 4; ++nb) {
            const int tok = t0 + wt + nb * 16 + m;
            ushort4 pk;
            pk.x = f2bf((aq[mb][nb][0] + bv4.x) * SCQ);
            pk.y = f2bf((aq[mb][nb][1] + bv4.y) * SCQ);
            pk.z = f2bf((aq[mb][nb][2] + bv4.z) * SCQ);
            pk.w = f2bf((aq[mb][nb][3] + bv4.w) * SCQ);
            *(ushort4*)(Qw + (size_t)tok * EMBED + feat) = pk;
        }
    }
    // ---- K epilogue ----
#pragma unroll
    for (int mb = 0; mb < 4; ++mb) {
        const int feat = f0 + wf + mb * 16 + quad * 4;
        float4 bv4 = *(const float4*)&bk[feat];
#pragma unroll
        for (int nb = 0; nb < 4; ++nb) {
            const int tok = t0 + wt + nb * 16 + m;
            ushort4 pk;
            pk.x = f2bf(ak[mb][nb][0] + bv4.x);
            pk.y = f2bf(ak[mb][nb][1] + bv4.y);
            pk.z = f2bf(ak[mb][nb][2] + bv4.z);
            pk.w = f2bf(ak[mb][nb][3] + bv4.w);
            *(ushort4*)(Kw + (size_t)tok * EMBED + feat) = pk;
        }
    }
    // ---- V epilogue: transposed, sigma-permuted column (bits 2<->3 of s&15) ----
    {
        const int h = (f0 + wf) >> 6;              // feat block is h-aligned (64)
#pragma unroll
        for (int nb = 0; nb < 4; ++nb) {
            const int tok = t0 + wt + nb * 16 + m;
            const int b   = tok >> 11;
            const int s   = tok & (SEQ - 1);
            const int sp  = (s & ~12) | ((s & 4) << 1) | ((s & 8) >> 1);
            const size_t base = ((size_t)(b * HEADS + h) * HDIM) * SEQ + sp;
#pragma unroll
            for (int mb = 0; mb < 4; ++mb) {
                const int feat  = f0 + wf + mb * 16 + quad * 4;
                const int dbase = mb * 16 + quad * 4;
                float4 bv4 = *(const float4*)&bv[feat];
                VtG[base + (size_t)(dbase + 0) * SEQ] = f2bf(av[mb][nb][0] + bv4.x);
                VtG[base + (size_t)(dbase + 1) * SEQ] = f2bf(av[mb][nb][1] + bv4.y);
                VtG[base + (size_t)(dbase + 2) * SEQ] = f2bf(av[mb][nb][2] + bv4.z);
                VtG[base + (size_t)(dbase + 3) * SEQ] = f2bf(av[mb][nb][3] + bv4.w);
            }
        }
    }
}

// ---------------------------------------------------------------------------
// MFMA flash attention, 32x32x16. R8 structure VERBATIM (best verified).
// dbuf issue-early/write-late pipeline; sigma-permuted V kills the permlane
// exchange; both QK^T chains hoisted; mask bitmask preload; mask fold via
// seed MFMA; lr = f32 tree-sum (R12's o2-MFMA denominator over the raw-D
// fragment FAILED correctness -- the ones-MFMA x sigma-fragment combination
// is layout-unsafe; tree-sum is the verified denominator); setprio.
// ---------------------------------------------------------------------------
__global__ __launch_bounds__(256, 4)
void attn_mfma(const unsigned short* __restrict__ Qb,
               const unsigned short* __restrict__ Kb,
               const unsigned short* __restrict__ VtG,
               const int* __restrict__ mask,
               unsigned short* __restrict__ Ob)
{
    __shared__ unsigned short Ks[2][64][72];  // [buf][key][d]
    __shared__ unsigned short Vs[2][64][72];  // [buf][d][key-sigma]

    const int tid  = threadIdx.x;
    // XCD-local remap: XCD = blockIdx.x % 8 gets 8 contiguous (b,h) groups
    const int lin  = (blockIdx.x & 7) * 128 + (blockIdx.x >> 3);
    const int qb   = lin & 15;
    const int h    = (lin >> 4) & 15;
    const int b    = lin >> 8;
    const int wid  = tid >> 6, lane = tid & 63;
    const int q32  = lane & 31, hi = lane >> 5;
    const int tb   = b * SEQ;
    const int q    = qb * 128 + wid * 32 + q32;

    // Q B-frags (pre-scaled): k = st*16 + hi*8 + j
    const unsigned short* qrow = Qb + (size_t)(tb + q) * EMBED + h * HDIM;
    short8 qf[4];
#pragma unroll
    for (int st = 0; st < 4; ++st)
        qf[st] = *(const short8*)(qrow + st * 16 + hi * 8);

    // mask bitmask: bit j = mask[j*32 + q32] (lane tests only keys == q32 mod 32)
    const int* mrow = mask + b * SEQ;
    unsigned long long mbits = 0;
#pragma unroll 8
    for (int j = 0; j < 64; ++j)
        mbits |= (unsigned long long)(mrow[j * 32 + q32] != 0 ? 1 : 0) << j;

    // mask B-frag: B[q][k]: nonzero only at k==0 (lanes hi==0, j==0)
    short8 mqf = {0, 0, 0, 0, 0, 0, 0, 0};
    mqf[0] = hi ? (short)0 : (short)0xC480;   // bf16(-1024), exact

    f32x16 o0, o1, z16;
#pragma unroll
    for (int i = 0; i < 16; ++i) { z16[i] = 0.f; }
    o0 = z16; o1 = z16;
    float lr = 0.f;

    // staging: thread -> (row = tid>>2, 16-elem col group = (tid&3)*16)
    const int sr = tid >> 2, sc = (tid & 3) * 16;
    const unsigned short* kSrc = Kb + (size_t)(tb + sr) * EMBED + h * HDIM + sc;
    const unsigned short* vSrc = VtG + ((size_t)(b * HEADS + h) * HDIM + sr) * SEQ + sc;

    // compute one 64-key tile from LDS buffers; jb = kt>>5 (mask bit base)
    auto compute = [&](const unsigned short (*Kc)[72],
                       const unsigned short (*Vc)[72], int jb) {
        __builtin_amdgcn_s_setprio(1);
        short8 mkfa = {0, 0, 0, 0, 0, 0, 0, 0};
        short8 mkfb = {0, 0, 0, 0, 0, 0, 0, 0};
        mkfa[0] = (hi == 0 && !((mbits >> jb) & 1))       ? (short)0x3F80 : (short)0;
        mkfb[0] = (hi == 0 && !((mbits >> (jb + 1)) & 1)) ? (short)0x3F80 : (short)0;

        // --- both QK^T chains first: matrix pipe fed during softmax below ---
        f32x16 s[2];
        s[0] = __builtin_amdgcn_mfma_f32_32x32x16_bf16(mkfa, mqf, z16, 0, 0, 0);
        s[1] = __builtin_amdgcn_mfma_f32_32x32x16_bf16(mkfb, mqf, z16, 0, 0, 0);
#pragma unroll
        for (int kb = 0; kb < 2; ++kb)
#pragma unroll
            for (int st = 0; st < 4; ++st) {
                short8 kf = *(const short8*)&Kc[kb * 32 + q32][st * 16 + hi * 8];
                s[kb] = __builtin_amdgcn_mfma_f32_32x32x16_bf16(kf, qf[st], s[kb], 0, 0, 0);
            }

#pragma unroll
        for (int kb = 0; kb < 2; ++kb) {
            // p = exp2(s); masked keys give exactly 0
            float p[16];
#pragma unroll
            for (int i = 0; i < 16; ++i) p[i] = __builtin_amdgcn_exp2f(s[kb][i]);

            // denominator: f32 tree-sum (masked p are exactly 0)
            lr += (((p[0] + p[1]) + (p[2] + p[3])) + ((p[4] + p[5]) + (p[6] + p[7])))
                + (((p[8] + p[9]) + (p[10] + p[11])) + ((p[12] + p[13]) + (p[14] + p[15])));

            unsigned D[8];
#pragma unroll
            for (int j = 0; j < 8; ++j) D[j] = cvtpk(p[2 * j], p[2 * j + 1]);

            // PV: B-frag = D directly (V is sigma-permuted); no permlane
#pragma unroll
            for (int cl = 0; cl < 2; ++cl) {
                union { uint4 u; short8 s8; } fr;
                fr.u.x = D[4 * cl + 0]; fr.u.y = D[4 * cl + 1];
                fr.u.z = D[4 * cl + 2]; fr.u.w = D[4 * cl + 3];

                const int kcol = kb * 32 + cl * 16 + hi * 8;
                short8 vf0 = *(const short8*)&Vc[q32][kcol];
                short8 vf1 = *(const short8*)&Vc[32 + q32][kcol];
                o0 = __builtin_amdgcn_mfma_f32_32x32x16_bf16(vf0, fr.s8, o0, 0, 0, 0);
                o1 = __builtin_amdgcn_mfma_f32_32x32x16_bf16(vf1, fr.s8, o1, 0, 0, 0);
            }
        }
        __builtin_amdgcn_s_setprio(0);
    };

    // ---- prologue: stage tile 0 into buf 0 ----
    {
        int4 kv0 = *(const int4*)(kSrc);
        int4 kv1 = *(const int4*)(kSrc + 8);
        int4 vv0 = *(const int4*)(vSrc);
        int4 vv1 = *(const int4*)(vSrc + 8);
        *(int4*)&Ks[0][sr][sc]     = kv0;
        *(int4*)&Ks[0][sr][sc + 8] = kv1;
        *(int4*)&Vs[0][sr][sc]     = vv0;
        *(int4*)&Vs[0][sr][sc + 8] = vv1;
        __syncthreads();
    }

    int cur = 0;
    for (int kt = 0; kt + 64 < SEQ; kt += 64) {
        // issue loads for tile kt+64 NOW; the compute below covers the latency
        const unsigned short* kp = kSrc + (size_t)(kt + 64) * EMBED;
        int4 kv0 = *(const int4*)(kp);
        int4 kv1 = *(const int4*)(kp + 8);
        int4 vv0 = *(const int4*)(vSrc + kt + 64);
        int4 vv1 = *(const int4*)(vSrc + kt + 64 + 8);

        compute(Ks[cur], Vs[cur], kt >> 5);

        __syncthreads();                      // A: all reads of buf[cur^1] long done
        const int nxt = cur ^ 1;
        *(int4*)&Ks[nxt][sr][sc]     = kv0;   // vmcnt drained here -- already landed
        *(int4*)&Ks[nxt][sr][sc + 8] = kv1;
        *(int4*)&Vs[nxt][sr][sc]     = vv0;
        *(int4*)&Vs[nxt][sr][sc + 8] = vv1;
        __syncthreads();                      // B: buf[nxt] ready for next compute
        cur = nxt;
    }
    compute(Ks[cur], Vs[cur], (SEQ - 64) >> 5);  // last tile

    // lr held half per hi-lane pair: combine, then normalize
    const float lrt = lr + __shfl_xor(lr, 32);
    const float inv = 1.0f / lrt;
    unsigned short* orow = Ob + (size_t)(tb + q) * EMBED + h * HDIM;
#pragma unroll
    for (int db = 0; db < 2; ++db) {
        const f32x16& oo = db ? o1 : o0;
#pragma unroll
        for (int qg = 0; qg < 4; ++qg) {
            ushort4 pk;
            pk.x = f2bf(oo[qg * 4 + 0] * inv);
            pk.y = f2bf(oo[qg * 4 + 1] * inv);
            pk.z = f2bf(oo[qg * 4 + 2] * inv);
            pk.w = f2bf(oo[qg * 4 + 3] * inv);
            *(ushort4*)(orow + db * 32 + qg * 8 + hi * 4) = pk;
        }
    }
}

// ---------------------------------------------------------------------------
// Output GEMM (R8 structure). fp32 out. XCD-local token swizzle.
// ---------------------------------------------------------------------------
__global__ __launch_bounds__(256, 2)
void gemm_o(const unsigned short* __restrict__ W, const unsigned short* __restrict__ X,
            const float* __restrict__ bias, float* __restrict__ Cout)
{
    __shared__ unsigned short Ws[2][128][32];
    __shared__ unsigned short Xs[2][128][32];

    const int tid  = threadIdx.x;
    const int bx   = blockIdx.x, by = blockIdx.y;
    const int f0   = (by >> 3) * 128;
    const int t0   = ((bx << 3) | (by & 7)) * 128;
    const int lane = tid & 63, m = lane & 15, quad = lane >> 4;
    const int wid  = tid >> 6;
    const int wf   = (wid & 1) * 64;
    const int wt   = (wid >> 1) * 64;

    const int r    = tid >> 2, cc = tid & 3, sw = (tid >> 4) & 3;
    const int gcol = (cc ^ sw) << 3;
    const unsigned short* Wp = W + (size_t)(f0 + r) * EMBED + gcol;
    const unsigned short* Xp = X + (size_t)(t0 + r) * EMBED + gcol;
    unsigned short* WsL[2] = { &Ws[0][0][0] + tid * 8, &Ws[1][0][0] + tid * 8 };
    unsigned short* XsL[2] = { &Xs[0][0][0] + tid * 8, &Xs[1][0][0] + tid * 8 };

    const int qs = (quad ^ ((m >> 2) & 3)) << 3;

    f32x4 acc[4][4] = {};

    for (int k0 = 0; k0 < EMBED; k0 += 64) {
        __syncthreads();
#pragma unroll
        for (int hf = 0; hf < 2; ++hf) {
            const int kk = k0 + hf * 32;
            gload_lds16(Wp + kk,              WsL[hf]);
            gload_lds16(Wp + kk + 64 * EMBED, WsL[hf] + 2048);
            gload_lds16(Xp + kk,              XsL[hf]);
            gload_lds16(Xp + kk + 64 * EMBED, XsL[hf] + 2048);
        }
        __syncthreads();

#pragma unroll
        for (int hf = 0; hf < 2; ++hf) {
            short8 af[4], bf4[4];
#pragma unroll
            for (int mb = 0; mb < 4; ++mb)
                af[mb] = *(const short8*)&Ws[hf][wf + mb * 16 + m][qs];
#pragma unroll
            for (int nb = 0; nb < 4; ++nb)
                bf4[nb] = *(const short8*)&Xs[hf][wt + nb * 16 + m][qs];
#pragma unroll
            for (int mb = 0; mb < 4; ++mb)
#pragma unroll
                for (int nb = 0; nb < 4; ++nb)
                    acc[mb][nb] = __builtin_amdgcn_mfma_f32_16x16x32_bf16(
                        af[mb], bf4[nb], acc[mb][nb], 0, 0, 0);
        }
    }

#pragma unroll
    for (int mb = 0; mb < 4; ++mb) {
        const int feat = f0 + wf + mb * 16 + quad * 4;
        float4 bv4 = *(const float4*)&bias[feat];
#pragma unroll
        for (int nb = 0; nb < 4; ++nb) {
            const int tok = t0 + wt + nb * 16 + m;
            float4 st;
            st.x = acc[mb][nb][0] + bv4.x;
            st.y = acc[mb][nb][1] + bv4.y;
            st.z = acc[mb][nb][2] + bv4.z;
            st.w = acc[mb][nb][3] + bv4.w;
            *(float4*)(Cout + (size_t)tok * EMBED + feat) = st;
        }
    }
}

// ---------------------------------------------------------------------------
extern "C" void kernel_launch(void* const* d_in, const int* in_sizes, int n_in,
                              void* d_out, int out_size, void* d_ws, size_t ws_size,
                              hipStream_t stream)
{
    const float* x    = (const float*)d_in[0];
    const int*   mask = (const int*)  d_in[1];
    const float* Wq   = (const float*)d_in[2];
    const float* bq   = (const float*)d_in[3];
    const float* Wk   = (const float*)d_in[4];
    const float* bk   = (const float*)d_in[5];
    const float* Wv   = (const float*)d_in[6];
    const float* bv   = (const float*)d_in[7];
    const float* Wo   = (const float*)d_in[8];
    const float* bo   = (const float*)d_in[9];
    float* out = (float*)d_out;

    const size_t NE = (size_t)NTOK * EMBED;
    const size_t WE = (size_t)EMBED * EMBED;
    unsigned short* Xb  = (unsigned short*)d_ws;
    unsigned short* Wqb = Xb + NE;            // Wq,Wk,Wv,Wo contiguous
    unsigned short* Wob = Wqb + 3 * WE;
    unsigned short* Qw  = Wob + WE;
    unsigned short* Kw  = Qw + NE;
    unsigned short* VtG = Kw + NE;            // [b*H+h][d][s-sigma], d = 0..63
    unsigned short* Ow  = Xb;                 // reuse: Xb dead after projections

    cast_all<<<4096 + 2048, 256, 0, stream>>>(x, Wq, Wk, Wv, Wo, Xb, Wqb);

    gemm_qkv<<<dim3(8, 64), 256, 0, stream>>>(Xb, Wqb, bq, bk, bv, Qw, Kw, VtG);

    attn_mfma<<<BATCH * HEADS * (SEQ / 128), 256, 0, stream>>>(Qw, Kw, VtG, mask, Ow);

    gemm_o<<<dim3(8, 64), 256, 0, stream>>>(Wob, Ow, bo, out);
}